// Round 8
// baseline (69.544 us; speedup 1.0000x reference)
//
#include <hip/hip_runtime.h>
#include <math.h>

// FBPINN: out(x) = sum_k w_k(x)*subnet_k(x) / sum_k w_k(x), x scalar in [0,1].
// Two dispatches (fusion abandoned: cg grid.sync ~60us, manual L3 barrier
// ~33us — both dwarf the ~4us/node they save; measured R5/R6):
//  1) build_tables: numerator table sum_k w_k*o_k at TBL grid points.
//     ONE LANE = ONE (point, slot) pair (wave = 16 pts x 4 subnet slots,
//     k = klo(point)+slot per-lane). Weights stream through VECTOR loads
//     (global_load_dwordx4, deep vmcnt pipelining, L1-broadcast for the ~5
//     distinct k per wave) instead of the R4 wave-uniform s_load chains that
//     were latency-bound (~250cyc each, shallowly pipelined => ~12us build).
//     Slot partials summed via 2x shfl_xor; lane slot==0 stores (coalesced).
//     No LDS, no syncthreads, no atomics, no zero-fill.
//  2) eval_lerp: float4 lerp of the table; denominator is ANALYTIC
//     (depends only on x: <=4 cosine windows). Kernel-boundary coherence.
// Lerp error ~2.5e-6 at TBL=16384 << 7.3e-3 threshold (bf16 floor 1.95e-3).

#define KSUB 16
#define NW 32
#define TBL 16384
#define BTHREADS 256

// tanh(x) = 1 - 2/(exp(2x)+1); v_exp_f32 is exp2 -> scale by 2*log2(e).
static __device__ __forceinline__ float fast_tanh(float v) {
    float e = __builtin_amdgcn_exp2f(v * 2.8853900817779268f);
    return 1.0f - 2.0f * __builtin_amdgcn_rcpf(e + 1.0f);
}

// cos(pi*u), u in [0,1]: v_cos_f32 takes revolutions.
static __device__ __forceinline__ float cos_pi(float u) {
    return __builtin_amdgcn_cosf(0.5f * u);
}

static __device__ __forceinline__ float window_w(float x, int k) {
    const float invTW = 20.0f;  // 1/0.05
    float xmin = (float)k * 0.0625f - 0.06f;
    float xmax = (float)(k + 1) * 0.0625f + 0.06f;
    float up = (x - xmin + 0.025f) * invTW;
    float dn = (xmax + 0.025f - x) * invTW;
    up = fminf(fmaxf(up, 0.0f), 1.0f);
    dn = fminf(fmaxf(dn, 0.0f), 1.0f);
    return 0.25f * (1.0f - cos_pi(up)) * (1.0f - cos_pi(dn));
}

// Active subnets at x: k in (16x-2.36, 16x+1.36) => at most 4, klo..klo+3.
static __device__ __forceinline__ float den_analytic(float xv) {
    int klo = (int)ceilf(16.0f * xv - 2.36f);
    float den = 0.f;
#pragma unroll
    for (int j = 0; j < 4; ++j) {
        int k = klo + j;
        if (k >= 0 && k < KSUB) den += window_w(xv, k);
    }
    return den;
}

// MLP 1->32->32->32->1, per-lane k, float4 vector weight loads.
static __device__ __forceinline__ float subnet_eval_vec(
    float xn, int kc,
    const float* __restrict__ W0, const float* __restrict__ B0,
    const float* __restrict__ W1, const float* __restrict__ B1,
    const float* __restrict__ W2, const float* __restrict__ B2,
    const float* __restrict__ W3, const float* __restrict__ B3)
{
    float h0[NW], h1[NW];
    // layer 0
    {
        const float4* w0v = reinterpret_cast<const float4*>(&W0[kc * NW]);
        const float4* b0v = reinterpret_cast<const float4*>(&B0[kc * NW]);
#pragma unroll
        for (int o4 = 0; o4 < NW / 4; ++o4) {
            float4 wv = w0v[o4], bv = b0v[o4];
            h0[4 * o4 + 0] = fast_tanh(fmaf(wv.x, xn, bv.x));
            h0[4 * o4 + 1] = fast_tanh(fmaf(wv.y, xn, bv.y));
            h0[4 * o4 + 2] = fast_tanh(fmaf(wv.z, xn, bv.z));
            h0[4 * o4 + 3] = fast_tanh(fmaf(wv.w, xn, bv.w));
        }
    }
    // layer 1
    {
        const float4* w1v = reinterpret_cast<const float4*>(&W1[kc * NW * NW]);
        const float* b1 = &B1[kc * NW];
#pragma unroll
        for (int o = 0; o < NW; ++o) {
            float a0 = b1[o], a1 = 0.f, a2 = 0.f, a3 = 0.f;
#pragma unroll
            for (int j4 = 0; j4 < NW / 4; ++j4) {
                float4 wv = w1v[o * (NW / 4) + j4];
                a0 = fmaf(wv.x, h0[4 * j4 + 0], a0);
                a1 = fmaf(wv.y, h0[4 * j4 + 1], a1);
                a2 = fmaf(wv.z, h0[4 * j4 + 2], a2);
                a3 = fmaf(wv.w, h0[4 * j4 + 3], a3);
            }
            h1[o] = fast_tanh((a0 + a1) + (a2 + a3));
        }
    }
    // layer 2
    {
        const float4* w2v = reinterpret_cast<const float4*>(&W2[kc * NW * NW]);
        const float* b2 = &B2[kc * NW];
#pragma unroll
        for (int o = 0; o < NW; ++o) {
            float a0 = b2[o], a1 = 0.f, a2 = 0.f, a3 = 0.f;
#pragma unroll
            for (int j4 = 0; j4 < NW / 4; ++j4) {
                float4 wv = w2v[o * (NW / 4) + j4];
                a0 = fmaf(wv.x, h1[4 * j4 + 0], a0);
                a1 = fmaf(wv.y, h1[4 * j4 + 1], a1);
                a2 = fmaf(wv.z, h1[4 * j4 + 2], a2);
                a3 = fmaf(wv.w, h1[4 * j4 + 3], a3);
            }
            h0[o] = fast_tanh((a0 + a1) + (a2 + a3));  // reuse h0 as h2
        }
    }
    // layer 3
    {
        const float4* w3v = reinterpret_cast<const float4*>(&W3[kc * NW]);
        float a0 = B3[kc], a1 = 0.f, a2 = 0.f, a3 = 0.f;
#pragma unroll
        for (int j4 = 0; j4 < NW / 4; ++j4) {
            float4 wv = w3v[j4];
            a0 = fmaf(wv.x, h0[4 * j4 + 0], a0);
            a1 = fmaf(wv.y, h0[4 * j4 + 1], a1);
            a2 = fmaf(wv.z, h0[4 * j4 + 2], a2);
            a3 = fmaf(wv.w, h0[4 * j4 + 3], a3);
        }
        return (a0 + a1) + (a2 + a3);
    }
}

// grid = TBL*4/BTHREADS blocks. Lane -> (point p = tid>>2, slot = tid&3).
__global__ __launch_bounds__(BTHREADS) void build_tables(
    const float* __restrict__ W0, const float* __restrict__ B0,
    const float* __restrict__ W1, const float* __restrict__ B1,
    const float* __restrict__ W2, const float* __restrict__ B2,
    const float* __restrict__ W3, const float* __restrict__ B3,
    float* __restrict__ gnum)
{
    const int tid = blockIdx.x * BTHREADS + threadIdx.x;
    const int p = tid >> 2;
    const int slot = tid & 3;
    const float inv = 1.0f / (float)(TBL - 1);
    const float xg = (float)p * inv;

    int klo = (int)ceilf(16.0f * xg - 2.36f);
    int k = klo + slot;
    int kc = min(max(k, 0), KSUB - 1);

    // xn: every subnet has scale 0.09125, center (k+0.5)/16
    const float INVS = 10.958904109589041f;  // 1/0.09125
    float xn = (xg - ((float)kc + 0.5f) * 0.0625f) * INVS;

    float w = window_w(xg, kc);
    float o = subnet_eval_vec(xn, kc, W0, B0, W1, B1, W2, B2, W3, B3);
    float val = (k >= 0 && k < KSUB && w > 0.0f) ? w * o : 0.0f;

    // sum the 4 slot partials (lanes l, l^1, l^2, l^3 share p)
    val += __shfl_xor(val, 1);
    val += __shfl_xor(val, 2);
    if (slot == 0) gnum[p] = val;  // 16 consecutive dwords per wave
}

// Lerp the numerator table; denominator computed analytically per point.
__global__ void eval_lerp(const float* __restrict__ x,
                          const float* __restrict__ gnum,
                          float* __restrict__ out, int N)
{
    const float scaleT = (float)(TBL - 1);
    int idx = blockIdx.x * blockDim.x + threadIdx.x;
    int base = idx * 4;
    if (base + 3 < N) {
        float4 xv = *reinterpret_cast<const float4*>(&x[base]);
        float4 r;
        float* rp = &r.x;
        const float* xp = &xv.x;
#pragma unroll
        for (int j = 0; j < 4; ++j) {
            float xj = xp[j];
            float t = fminf(fmaxf(xj * scaleT, 0.0f), scaleT);
            int i0 = (int)t;
            if (i0 > TBL - 2) i0 = TBL - 2;
            float f = t - (float)i0;
            float n0 = gnum[i0], n1 = gnum[i0 + 1];
            float num = fmaf(f, n1 - n0, n0);
            float den = den_analytic(xj);
            rp[j] = num * __builtin_amdgcn_rcpf(den + 1e-12f);
        }
        *reinterpret_cast<float4*>(&out[base]) = r;
    } else {
        for (int j = base; j < N; ++j) {
            float xj = x[j];
            float t = fminf(fmaxf(xj * scaleT, 0.0f), scaleT);
            int i0 = (int)t;
            if (i0 > TBL - 2) i0 = TBL - 2;
            float f = t - (float)i0;
            float num = fmaf(f, gnum[i0 + 1] - gnum[i0], gnum[i0]);
            float den = den_analytic(xj);
            out[j] = num * __builtin_amdgcn_rcpf(den + 1e-12f);
        }
    }
}

// Fallback if ws_size is tiny: direct evaluation (correct, slower).
__global__ void direct_eval(
    const float* __restrict__ x,
    const float* __restrict__ W0, const float* __restrict__ B0,
    const float* __restrict__ W1, const float* __restrict__ B1,
    const float* __restrict__ W2, const float* __restrict__ B2,
    const float* __restrict__ W3, const float* __restrict__ B3,
    float* __restrict__ out, int N)
{
    int n = blockIdx.x * blockDim.x + threadIdx.x;
    if (n >= N) return;
    float xv = x[n];
    float num = 0.f, den = 0.f;
    for (int k = 0; k < KSUB; ++k) {
        float w = window_w(xv, k);
        if (w <= 0.0f) continue;
        float xn = (xv - ((float)k + 0.5f) * 0.0625f) * 10.958904109589041f;
        float o = subnet_eval_vec(xn, k, W0, B0, W1, B1, W2, B2, W3, B3);
        num += w * o;
        den += w;
    }
    out[n] = num * __builtin_amdgcn_rcpf(den + 1e-12f);
}

extern "C" void kernel_launch(void* const* d_in, const int* in_sizes, int n_in,
                              void* d_out, int out_size, void* d_ws, size_t ws_size,
                              hipStream_t stream) {
    const float* x  = (const float*)d_in[0];
    const float* W0 = (const float*)d_in[1];
    const float* B0 = (const float*)d_in[2];
    const float* W1 = (const float*)d_in[3];
    const float* B1 = (const float*)d_in[4];
    const float* W2 = (const float*)d_in[5];
    const float* B2 = (const float*)d_in[6];
    const float* W3 = (const float*)d_in[7];
    const float* B3 = (const float*)d_in[8];
    float* out = (float*)d_out;
    const int N = in_sizes[0];

    if ((size_t)TBL * 4 <= ws_size) {
        float* gnum = (float*)d_ws;
        build_tables<<<TBL * 4 / BTHREADS, BTHREADS, 0, stream>>>(
            W0, B0, W1, B1, W2, B2, W3, B3, gnum);
        int nv = (N + 3) / 4;
        eval_lerp<<<(nv + 255) / 256, 256, 0, stream>>>(x, gnum, out, N);
    } else {
        direct_eval<<<(N + 255) / 256, 256, 0, stream>>>(
            x, W0, B0, W1, B1, W2, B2, W3, B3, out, N);
    }
}

// Round 9
// 19.217 us; speedup vs baseline: 3.6190x; 3.6190x over previous
//
#include <hip/hip_runtime.h>
#include <math.h>

// FBPINN: out(x) = sum_k w_k(x)*subnet_k(x) / sum_k w_k(x), x scalar in [0,1].
// Two dispatches (fusion abandoned: cg grid.sync ~60us, manual L3 barrier
// ~33us; measured R5/R6):
//  1) build_tables: numerator table sum_k w_k*o_k at TBL grid points.
//     Block = 256 thr (4 waves) per 64-pt stretch; wave w = subnet slot
//     klo_b+w (wave-uniform). Weight delivery = LDS BROADCAST: each wave
//     stages its slot's 8.8KB weights into its own LDS region with 9
//     coalesced float4 loads/lane (one memory round-trip, deep vmcnt
//     pipelining), then evaluates with ds_read_b128 broadcasts (~few cyc,
//     conflict-free). Kills both failure modes measured so far: s_load
//     chains (R4: ~12us) and per-lane divergent VMEM (R7: ~60us).
//     Partials via LDS part[], one dense store. No atomics, no zero-fill.
//  2) eval_lerp: float4 lerp of the table; denominator ANALYTIC (<=4
//     cosine windows of x only). Kernel-boundary coherence (R1-R4 proven).
// Lerp error ~2.5e-6 at TBL=16384 << 7.3e-3 threshold (bf16 floor 1.95e-3).

#define KSUB 16
#define NW 32
#define TBL 16384
#define SLOTS 4          // union of active k over a 64-pt stretch: width
                         // 3.72+0.0615 < 4 -> at most 4 ints, klo_b..klo_b+3
#define BTHREADS 256
// per-slot LDS region (floats): W1[1024] W2[1024] | W0 B0 B1 B2 W3 @2048.. | pad
#define RSTRIDE 2304
#define OW1 0
#define OW2 1024
#define OW0 2048
#define OB0 2080
#define OB1 2112
#define OB2 2144
#define OW3 2176

// tanh(x) = 1 - 2/(exp(2x)+1); v_exp_f32 is exp2 -> scale by 2*log2(e).
static __device__ __forceinline__ float fast_tanh(float v) {
    float e = __builtin_amdgcn_exp2f(v * 2.8853900817779268f);
    return 1.0f - 2.0f * __builtin_amdgcn_rcpf(e + 1.0f);
}

// cos(pi*u), u in [0,1]: v_cos_f32 takes revolutions.
static __device__ __forceinline__ float cos_pi(float u) {
    return __builtin_amdgcn_cosf(0.5f * u);
}

static __device__ __forceinline__ float window_w(float x, int k) {
    const float invTW = 20.0f;  // 1/0.05
    float xmin = (float)k * 0.0625f - 0.06f;
    float xmax = (float)(k + 1) * 0.0625f + 0.06f;
    float up = (x - xmin + 0.025f) * invTW;
    float dn = (xmax + 0.025f - x) * invTW;
    up = fminf(fmaxf(up, 0.0f), 1.0f);
    dn = fminf(fmaxf(dn, 0.0f), 1.0f);
    return 0.25f * (1.0f - cos_pi(up)) * (1.0f - cos_pi(dn));
}

// Active subnets at x: k in (16x-2.36, 16x+1.36) => at most 4, klo..klo+3.
static __device__ __forceinline__ float den_analytic(float xv) {
    int klo = (int)ceilf(16.0f * xv - 2.36f);
    float den = 0.f;
#pragma unroll
    for (int j = 0; j < 4; ++j) {
        int k = klo + j;
        if (k >= 0 && k < KSUB) den += window_w(xv, k);
    }
    return den;
}

// grid = TBL/64 blocks x 256 threads (4 waves). See header.
__global__ __launch_bounds__(BTHREADS) void build_tables(
    const float* __restrict__ W0, const float* __restrict__ B0,
    const float* __restrict__ W1, const float* __restrict__ B1,
    const float* __restrict__ W2, const float* __restrict__ B2,
    const float* __restrict__ W3, const float* __restrict__ B3,
    float* __restrict__ gnum)
{
    __shared__ float lds[SLOTS * RSTRIDE];   // 36 KB weight regions
    __shared__ float part[SLOTS][64];

    const int lane = threadIdx.x & 63;
    const int wv   = threadIdx.x >> 6;       // wave id = subnet slot
    const int bx   = blockIdx.x;
    const int i    = bx * 64 + lane;
    const float inv = 1.0f / (float)(TBL - 1);
    const float xg  = (float)i * inv;

    float x_lo = (float)(bx * 64) * inv;
    int klo_b = (int)ceilf(16.0f * x_lo - 2.36f);
    const int k  = klo_b + wv;               // wave-uniform
    const int kc = min(max(k, 0), KSUB - 1);

    // ---- stage this wave's weight region (own region -> no barrier) ----
    float* R = &lds[wv * RSTRIDE];
    {
        const float4* gW1 = reinterpret_cast<const float4*>(&W1[kc * NW * NW]);
        const float4* gW2 = reinterpret_cast<const float4*>(&W2[kc * NW * NW]);
        float4 t0 = gW1[0 * 64 + lane];
        float4 t1 = gW1[1 * 64 + lane];
        float4 t2 = gW1[2 * 64 + lane];
        float4 t3 = gW1[3 * 64 + lane];
        float4 t4 = gW2[0 * 64 + lane];
        float4 t5 = gW2[1 * 64 + lane];
        float4 t6 = gW2[2 * 64 + lane];
        float4 t7 = gW2[3 * 64 + lane];
        float4 t8;
        const int a = lane >> 3;             // 0..7 (use 0..4)
        const int e = (lane & 7) * 4;
        const float* sp = (a == 0) ? &W0[kc * NW] :
                          (a == 1) ? &B0[kc * NW] :
                          (a == 2) ? &B1[kc * NW] :
                          (a == 3) ? &B2[kc * NW] : &W3[kc * NW];
        if (a < 5) t8 = *reinterpret_cast<const float4*>(&sp[e]);
        *reinterpret_cast<float4*>(&R[OW1 + 0 * 256 + lane * 4]) = t0;
        *reinterpret_cast<float4*>(&R[OW1 + 1 * 256 + lane * 4]) = t1;
        *reinterpret_cast<float4*>(&R[OW1 + 2 * 256 + lane * 4]) = t2;
        *reinterpret_cast<float4*>(&R[OW1 + 3 * 256 + lane * 4]) = t3;
        *reinterpret_cast<float4*>(&R[OW2 + 0 * 256 + lane * 4]) = t4;
        *reinterpret_cast<float4*>(&R[OW2 + 1 * 256 + lane * 4]) = t5;
        *reinterpret_cast<float4*>(&R[OW2 + 2 * 256 + lane * 4]) = t6;
        *reinterpret_cast<float4*>(&R[OW2 + 3 * 256 + lane * 4]) = t7;
        if (a < 5)
            *reinterpret_cast<float4*>(&R[OW0 + a * 32 + e]) = t8;
    }
    // same-wave ds_write -> ds_read ordering is handled by lgkmcnt.

    // ---- evaluate subnet kc at this lane's point, weights from LDS ----
    const float INVS = 10.958904109589041f;  // 1/0.09125 (uniform scale)
    float xn = (xg - ((float)kc + 0.5f) * 0.0625f) * INVS;

    float h0[NW], h1[NW];
    // layer 0
#pragma unroll
    for (int o4 = 0; o4 < NW / 4; ++o4) {
        float4 wvv = *reinterpret_cast<const float4*>(&R[OW0 + 4 * o4]);
        float4 bv  = *reinterpret_cast<const float4*>(&R[OB0 + 4 * o4]);
        h0[4 * o4 + 0] = fast_tanh(fmaf(wvv.x, xn, bv.x));
        h0[4 * o4 + 1] = fast_tanh(fmaf(wvv.y, xn, bv.y));
        h0[4 * o4 + 2] = fast_tanh(fmaf(wvv.z, xn, bv.z));
        h0[4 * o4 + 3] = fast_tanh(fmaf(wvv.w, xn, bv.w));
    }
    // layer 1
#pragma unroll
    for (int o = 0; o < NW; ++o) {
        float a0 = R[OB1 + o], a1 = 0.f, a2 = 0.f, a3 = 0.f;
#pragma unroll
        for (int j4 = 0; j4 < NW / 4; ++j4) {
            float4 wvv = *reinterpret_cast<const float4*>(&R[OW1 + o * NW + 4 * j4]);
            a0 = fmaf(wvv.x, h0[4 * j4 + 0], a0);
            a1 = fmaf(wvv.y, h0[4 * j4 + 1], a1);
            a2 = fmaf(wvv.z, h0[4 * j4 + 2], a2);
            a3 = fmaf(wvv.w, h0[4 * j4 + 3], a3);
        }
        h1[o] = fast_tanh((a0 + a1) + (a2 + a3));
    }
    // layer 2
#pragma unroll
    for (int o = 0; o < NW; ++o) {
        float a0 = R[OB2 + o], a1 = 0.f, a2 = 0.f, a3 = 0.f;
#pragma unroll
        for (int j4 = 0; j4 < NW / 4; ++j4) {
            float4 wvv = *reinterpret_cast<const float4*>(&R[OW2 + o * NW + 4 * j4]);
            a0 = fmaf(wvv.x, h1[4 * j4 + 0], a0);
            a1 = fmaf(wvv.y, h1[4 * j4 + 1], a1);
            a2 = fmaf(wvv.z, h1[4 * j4 + 2], a2);
            a3 = fmaf(wvv.w, h1[4 * j4 + 3], a3);
        }
        h0[o] = fast_tanh((a0 + a1) + (a2 + a3));  // reuse h0 as h2
    }
    // layer 3
    float out_o;
    {
        float a0 = B3[kc], a1 = 0.f, a2 = 0.f, a3 = 0.f;
#pragma unroll
        for (int j4 = 0; j4 < NW / 4; ++j4) {
            float4 wvv = *reinterpret_cast<const float4*>(&R[OW3 + 4 * j4]);
            a0 = fmaf(wvv.x, h0[4 * j4 + 0], a0);
            a1 = fmaf(wvv.y, h0[4 * j4 + 1], a1);
            a2 = fmaf(wvv.z, h0[4 * j4 + 2], a2);
            a3 = fmaf(wvv.w, h0[4 * j4 + 3], a3);
        }
        out_o = (a0 + a1) + (a2 + a3);
    }

    float wgt = window_w(xg, kc);
    part[wv][lane] = (k >= 0 && k < KSUB) ? wgt * out_o : 0.0f;
    __syncthreads();
    if (threadIdx.x < 64) {
        gnum[i] = (part[0][lane] + part[1][lane]) +
                  (part[2][lane] + part[3][lane]);
    }
}

// Lerp the numerator table; denominator computed analytically per point.
__global__ void eval_lerp(const float* __restrict__ x,
                          const float* __restrict__ gnum,
                          float* __restrict__ out, int N)
{
    const float scaleT = (float)(TBL - 1);
    int idx = blockIdx.x * blockDim.x + threadIdx.x;
    int base = idx * 4;
    if (base + 3 < N) {
        float4 xv = *reinterpret_cast<const float4*>(&x[base]);
        float4 r;
        float* rp = &r.x;
        const float* xp = &xv.x;
#pragma unroll
        for (int j = 0; j < 4; ++j) {
            float xj = xp[j];
            float t = fminf(fmaxf(xj * scaleT, 0.0f), scaleT);
            int i0 = (int)t;
            if (i0 > TBL - 2) i0 = TBL - 2;
            float f = t - (float)i0;
            float n0 = gnum[i0], n1 = gnum[i0 + 1];
            float num = fmaf(f, n1 - n0, n0);
            float den = den_analytic(xj);
            rp[j] = num * __builtin_amdgcn_rcpf(den + 1e-12f);
        }
        *reinterpret_cast<float4*>(&out[base]) = r;
    } else {
        for (int j = base; j < N; ++j) {
            float xj = x[j];
            float t = fminf(fmaxf(xj * scaleT, 0.0f), scaleT);
            int i0 = (int)t;
            if (i0 > TBL - 2) i0 = TBL - 2;
            float f = t - (float)i0;
            float num = fmaf(f, gnum[i0 + 1] - gnum[i0], gnum[i0]);
            float den = den_analytic(xj);
            out[j] = num * __builtin_amdgcn_rcpf(den + 1e-12f);
        }
    }
}

// ---- fallback path (tiny ws only): direct evaluation via global loads ----
static __device__ __forceinline__ float subnet_eval_g(
    float xn, int kc,
    const float* __restrict__ W0, const float* __restrict__ B0,
    const float* __restrict__ W1, const float* __restrict__ B1,
    const float* __restrict__ W2, const float* __restrict__ B2,
    const float* __restrict__ W3, const float* __restrict__ B3)
{
    float h0[NW], h1[NW];
#pragma unroll
    for (int o = 0; o < NW; ++o)
        h0[o] = fast_tanh(fmaf(W0[kc * NW + o], xn, B0[kc * NW + o]));
#pragma unroll
    for (int o = 0; o < NW; ++o) {
        float a = B1[kc * NW + o];
        const float* row = &W1[kc * NW * NW + o * NW];
#pragma unroll
        for (int j = 0; j < NW; ++j) a = fmaf(row[j], h0[j], a);
        h1[o] = fast_tanh(a);
    }
#pragma unroll
    for (int o = 0; o < NW; ++o) {
        float a = B2[kc * NW + o];
        const float* row = &W2[kc * NW * NW + o * NW];
#pragma unroll
        for (int j = 0; j < NW; ++j) a = fmaf(row[j], h1[j], a);
        h0[o] = fast_tanh(a);
    }
    float a = B3[kc];
#pragma unroll
    for (int j = 0; j < NW; ++j) a = fmaf(W3[kc * NW + j], h0[j], a);
    return a;
}

__global__ void direct_eval(
    const float* __restrict__ x,
    const float* __restrict__ W0, const float* __restrict__ B0,
    const float* __restrict__ W1, const float* __restrict__ B1,
    const float* __restrict__ W2, const float* __restrict__ B2,
    const float* __restrict__ W3, const float* __restrict__ B3,
    float* __restrict__ out, int N)
{
    int n = blockIdx.x * blockDim.x + threadIdx.x;
    if (n >= N) return;
    float xv = x[n];
    float num = 0.f, den = 0.f;
    for (int k = 0; k < KSUB; ++k) {
        float w = window_w(xv, k);
        if (w <= 0.0f) continue;
        float xn = (xv - ((float)k + 0.5f) * 0.0625f) * 10.958904109589041f;
        float o = subnet_eval_g(xn, k, W0, B0, W1, B1, W2, B2, W3, B3);
        num += w * o;
        den += w;
    }
    out[n] = num * __builtin_amdgcn_rcpf(den + 1e-12f);
}

extern "C" void kernel_launch(void* const* d_in, const int* in_sizes, int n_in,
                              void* d_out, int out_size, void* d_ws, size_t ws_size,
                              hipStream_t stream) {
    const float* x  = (const float*)d_in[0];
    const float* W0 = (const float*)d_in[1];
    const float* B0 = (const float*)d_in[2];
    const float* W1 = (const float*)d_in[3];
    const float* B1 = (const float*)d_in[4];
    const float* W2 = (const float*)d_in[5];
    const float* B2 = (const float*)d_in[6];
    const float* W3 = (const float*)d_in[7];
    const float* B3 = (const float*)d_in[8];
    float* out = (float*)d_out;
    const int N = in_sizes[0];

    if ((size_t)TBL * 4 <= ws_size) {
        float* gnum = (float*)d_ws;
        build_tables<<<TBL / 64, BTHREADS, 0, stream>>>(
            W0, B0, W1, B1, W2, B2, W3, B3, gnum);
        int nv = (N + 3) / 4;
        eval_lerp<<<(nv + 255) / 256, 256, 0, stream>>>(x, gnum, out, N);
    } else {
        direct_eval<<<(N + 255) / 256, 256, 0, stream>>>(
            x, W0, B0, W1, B1, W2, B2, W3, B3, out, N);
    }
}